// Round 2
// baseline (1772.005 us; speedup 1.0000x reference)
//
#include <hip/hip_runtime.h>
#include <math.h>

#define C1F 1.0e-4f   // 0.01^2
#define C2F 9.0e-4f   // 0.03^2

// acc layout: per scale i (0..3), base = i*8
//  +0: sum |left_est - lpy|      +1: sum |right_est - rpy|
//  +2: sum |rl_disp - dl|        +3: sum |lr_disp - dr|
//  +4: sum x-grad smooth (dl+dr) +5: sum y-grad smooth (dl+dr)
//  +6: sum ssim_l (clipped)      +7: sum ssim_r

__device__ __forceinline__ void warp_coeffs(float px, int W, int& i0, int& i1,
                                            float& w0, float& w1) {
    float x0f = floorf(px);
    float f = px - x0f;
    int x0i = (int)x0f;
    int x1i = x0i + 1;
    float v0 = (x0i >= 0 && x0i < W) ? 1.f : 0.f;
    float v1 = (x1i >= 0 && x1i < W) ? 1.f : 0.f;
    i0 = min(max(x0i, 0), W - 1);
    i1 = min(max(x1i, 0), W - 1);
    w0 = v0 * (1.f - f);
    w1 = v1 * f;
}

template<int N>
__device__ __forceinline__ void block_acc(const float* vals, float* gacc) {
    __shared__ float sacc[N];
    if (threadIdx.x < N) sacc[threadIdx.x] = 0.f;
    __syncthreads();
#pragma unroll
    for (int k = 0; k < N; ++k) {
        float v = vals[k];
#pragma unroll
        for (int off = 32; off > 0; off >>= 1) v += __shfl_down(v, off, 64);
        if ((threadIdx.x & 63) == 0) atomicAdd(&sacc[k], v);
    }
    __syncthreads();
    if (threadIdx.x < N) atomicAdd(&gacc[threadIdx.x], sacc[threadIdx.x]);
}

__global__ void k_zero(float* acc) {
    if (threadIdx.x < 64) acc[threadIdx.x] = 0.f;
}

// Bilinear align-corners resize of left+right full-res images to (oh, ow).
__global__ void __launch_bounds__(256, 4)
k_resize(const float* __restrict__ left, const float* __restrict__ right,
         float* __restrict__ lo, float* __restrict__ ro,
         int B, int H, int W, int oh, int ow) {
    long long idx = (long long)blockIdx.x * blockDim.x + threadIdx.x;
    long long total = (long long)B * 3 * oh * ow;
    if (idx >= 2 * total) return;
    const float* src = left;
    float* dst = lo;
    if (idx >= total) { src = right; dst = ro; idx -= total; }
    int x = (int)(idx % ow);
    long long t = idx / ow;
    int y = (int)(t % oh);
    t /= oh;
    int c = (int)(t % 3);
    int b = (int)(t / 3);
    float sy = (float)(H - 1) / (float)(oh - 1);
    float sx = (float)(W - 1) / (float)(ow - 1);
    float fy = y * sy;
    float fx = x * sx;
    int y0 = (int)floorf(fy); float wy = fy - (float)y0;
    int x0 = (int)floorf(fx); float wx = fx - (float)x0;
    int y1 = min(y0 + 1, H - 1); y0 = min(y0, H - 1);
    int x1 = min(x0 + 1, W - 1); x0 = min(x0, W - 1);
    const float* p = src + (((long long)b * 3 + c) * H) * W;
    float a00 = p[(long long)y0 * W + x0];
    float a10 = p[(long long)y1 * W + x0];
    float a01 = p[(long long)y0 * W + x1];
    float a11 = p[(long long)y1 * W + x1];
    float r0 = a00 * (1.f - wy) + a10 * wy;
    float r1 = a01 * (1.f - wy) + a11 * wy;
    dst[(((long long)b * 3 + c) * oh + y) * ow + x] = r0 * (1.f - wx) + r1 * wx;
}

// Per-pixel: warp L1 (both sides) + LR-consistency + edge-aware smoothness.
__global__ void __launch_bounds__(256, 4)
k_warp_smooth(const float* __restrict__ disp, const float* __restrict__ lpy,
              const float* __restrict__ rpy, float* __restrict__ acc,
              int B, int h, int w) {
    long long idx = (long long)blockIdx.x * blockDim.x + threadIdx.x;
    long long total = (long long)B * h * w;
    float sums[6] = {0.f, 0.f, 0.f, 0.f, 0.f, 0.f};
    if (idx < total) {
        int x = (int)(idx % w);
        int y = (int)((idx / w) % h);
        int b = (int)(idx / ((long long)w * h));
        const float* dl_row = disp + (((long long)b * 2 + 0) * h + y) * w;
        const float* dr_row = disp + (((long long)b * 2 + 1) * h + y) * w;
        float dl = dl_row[x], dr = dr_row[x];
        float invWm1 = 1.f / (float)(w - 1);
        float xb = (float)x * invWm1;
        int i0, i1; float w0, w1;
        // left_est = warp(rpy, dl, -1); rl_disp = warp(dr, dl, -1)
        warp_coeffs((xb - dl) * (float)(w - 1), w, i0, i1, w0, w1);
#pragma unroll
        for (int c = 0; c < 3; ++c) {
            const float* rrow = rpy + (((long long)b * 3 + c) * h + y) * w;
            const float* lrow = lpy + (((long long)b * 3 + c) * h + y) * w;
            float le = rrow[i0] * w0 + rrow[i1] * w1;
            sums[0] += fabsf(le - lrow[x]);
        }
        float rl = dr_row[i0] * w0 + dr_row[i1] * w1;
        sums[2] += fabsf(rl - dl);
        // right_est = warp(lpy, dr, +1); lr_disp = warp(dl, dr, +1)
        warp_coeffs((xb + dr) * (float)(w - 1), w, i0, i1, w0, w1);
#pragma unroll
        for (int c = 0; c < 3; ++c) {
            const float* rrow = rpy + (((long long)b * 3 + c) * h + y) * w;
            const float* lrow = lpy + (((long long)b * 3 + c) * h + y) * w;
            float re = lrow[i0] * w0 + lrow[i1] * w1;
            sums[1] += fabsf(re - rrow[x]);
        }
        float lr = dl_row[i0] * w0 + dl_row[i1] * w1;
        sums[3] += fabsf(lr - dr);
        // smoothness
        const float third = 1.f / 3.f;
        if (x < w - 1) {
            float dgl = dl - dl_row[x + 1];
            float dgr = dr - dr_row[x + 1];
            float al = 0.f, ar = 0.f;
#pragma unroll
            for (int c = 0; c < 3; ++c) {
                const float* lrow = lpy + (((long long)b * 3 + c) * h + y) * w;
                const float* rrow = rpy + (((long long)b * 3 + c) * h + y) * w;
                al += fabsf(lrow[x] - lrow[x + 1]);
                ar += fabsf(rrow[x] - rrow[x + 1]);
            }
            sums[4] += fabsf(dgl * expf(-al * third)) + fabsf(dgr * expf(-ar * third));
        }
        if (y < h - 1) {
            float dgl = dl - dl_row[x + w];
            float dgr = dr - dr_row[x + w];
            float al = 0.f, ar = 0.f;
#pragma unroll
            for (int c = 0; c < 3; ++c) {
                const float* lrow = lpy + (((long long)b * 3 + c) * h + y) * w;
                const float* rrow = rpy + (((long long)b * 3 + c) * h + y) * w;
                al += fabsf(lrow[x] - lrow[x + w]);
                ar += fabsf(rrow[x] - rrow[x + w]);
            }
            sums[5] += fabsf(dgl * expf(-al * third)) + fabsf(dgr * expf(-ar * third));
        }
    }
    block_acc<6>(sums, acc);   // slots base+0..5
}

// SSIM over 3x3 valid windows, channel-outer to keep register pressure low
// (R1 version held 30 accumulators -> scratch spill: 603 MB WRITE_SIZE).
__global__ void __launch_bounds__(256, 4)
k_ssim(const float* __restrict__ disp, const float* __restrict__ lpy,
       const float* __restrict__ rpy, float* __restrict__ acc,
       int B, int h, int w) {
    int ho = h - 2, wo = w - 2;
    long long idx = (long long)blockIdx.x * blockDim.x + threadIdx.x;
    long long total = (long long)B * ho * wo;
    float sums[2] = {0.f, 0.f};
    if (idx < total) {
        int xo = (int)(idx % wo);
        int yo = (int)((idx / wo) % ho);
        int b = (int)(idx / ((long long)wo * ho));
        float invWm1 = 1.f / (float)(w - 1);
        float Wm1 = (float)(w - 1);
        const float* dl_base = disp + (((long long)b * 2 + 0) * h) * w;
        const float* dr_base = disp + (((long long)b * 2 + 1) * h) * w;
        const float inv9 = 1.f / 9.f;
        for (int c = 0; c < 3; ++c) {
            const float* lbase = lpy + (((long long)b * 3 + c) * h) * w;
            const float* rbase = rpy + (((long long)b * 3 + c) * h) * w;
            float sLx = 0.f, sLy = 0.f, sLxx = 0.f, sLyy = 0.f, sLxy = 0.f;
            float sRx = 0.f, sRy = 0.f, sRxx = 0.f, sRyy = 0.f, sRxy = 0.f;
#pragma unroll
            for (int dy = 0; dy < 3; ++dy) {
                int y = yo + dy;
                const float* dl_row = dl_base + (long long)y * w;
                const float* dr_row = dr_base + (long long)y * w;
                const float* lrow = lbase + (long long)y * w;
                const float* rrow = rbase + (long long)y * w;
#pragma unroll
                for (int dx = 0; dx < 3; ++dx) {
                    int x = xo + dx;
                    float dl = dl_row[x], dr = dr_row[x];
                    float xb = (float)x * invWm1;
                    int i0, i1; float w0, w1;
                    warp_coeffs((xb - dl) * Wm1, w, i0, i1, w0, w1);
                    float le = rrow[i0] * w0 + rrow[i1] * w1;   // x (left side)
                    float lv = lrow[x];                          // y (left side)
                    sLx += le; sLy += lv;
                    sLxx += le * le; sLyy += lv * lv; sLxy += le * lv;
                    warp_coeffs((xb + dr) * Wm1, w, i0, i1, w0, w1);
                    float re = lrow[i0] * w0 + lrow[i1] * w1;   // x (right side)
                    float rv = rrow[x];                          // y (right side)
                    sRx += re; sRy += rv;
                    sRxx += re * re; sRyy += rv * rv; sRxy += re * rv;
                }
            }
            {
                float mx = sLx * inv9, my = sLy * inv9;
                float vx = sLxx * inv9 - mx * mx;
                float vy = sLyy * inv9 - my * my;
                float vxy = sLxy * inv9 - mx * my;
                float s = (2.f * mx * my + C1F) * (2.f * vxy + C2F) /
                          ((mx * mx + my * my + C1F) * (vx + vy + C2F));
                float v = (1.f - s) * 0.5f;
                sums[0] += fminf(fmaxf(v, 0.f), 1.f);
            }
            {
                float mx = sRx * inv9, my = sRy * inv9;
                float vx = sRxx * inv9 - mx * mx;
                float vy = sRyy * inv9 - my * my;
                float vxy = sRxy * inv9 - mx * my;
                float s = (2.f * mx * my + C1F) * (2.f * vxy + C2F) /
                          ((mx * mx + my * my + C1F) * (vx + vy + C2F));
                float v = (1.f - s) * 0.5f;
                sums[1] += fminf(fmaxf(v, 0.f), 1.f);
            }
        }
    }
    block_acc<2>(sums, acc + 6);   // slots base+6,7
}

__global__ void k_final(const float* __restrict__ acc, float* __restrict__ out,
                        int B, int H, int W) {
    if (threadIdx.x != 0 || blockIdx.x != 0) return;
    float img = 0.f, lr = 0.f, sm = 0.f;
    for (int i = 0; i < 4; ++i) {
        int r = 1 << i;
        int h = H / r, w = W / r;
        const float* a = acc + i * 8;
        float Nl1 = (float)B * 3.f * (float)h * (float)w;
        float Nss = (float)B * 3.f * (float)(h - 2) * (float)(w - 2);
        float Nlr = (float)B * (float)h * (float)w;
        float Nsx = (float)B * (float)h * (float)(w - 1);
        float Nsy = (float)B * (float)(h - 1) * (float)w;
        img += 0.5f * (a[6] / Nss) + 0.5f * (a[0] / Nl1)
             + 0.5f * (a[7] / Nss) + 0.5f * (a[1] / Nl1);
        lr += a[2] / Nlr + a[3] / Nlr;
        sm += (a[4] / Nsx + a[5] / Nsy) / (float)r;
    }
    out[0] = img + 0.1f * sm + 1.0f * lr;
}

extern "C" void kernel_launch(void* const* d_in, const int* in_sizes, int n_in,
                              void* d_out, int out_size, void* d_ws, size_t ws_size,
                              hipStream_t stream) {
    const int B = 16, H = 384, W = 768;
    const float* disp[4] = {(const float*)d_in[0], (const float*)d_in[1],
                            (const float*)d_in[2], (const float*)d_in[3]};
    const float* left = (const float*)d_in[4];
    const float* right = (const float*)d_in[5];
    float* out = (float*)d_out;

    float* acc = (float*)d_ws;
    float* pyr = acc + 256;
    long long sz1 = (long long)B * 3 * (H / 2) * (W / 2);
    long long sz2 = (long long)B * 3 * (H / 4) * (W / 4);
    long long sz3 = (long long)B * 3 * (H / 8) * (W / 8);
    float* lp1 = pyr;
    float* rp1 = lp1 + sz1;
    float* lp2 = rp1 + sz1;
    float* rp2 = lp2 + sz2;
    float* lp3 = rp2 + sz2;
    float* rp3 = lp3 + sz3;

    const int TB = 256;
    hipLaunchKernelGGL(k_zero, dim3(1), dim3(64), 0, stream, acc);

    {
        long long t1 = 2 * sz1, t2 = 2 * sz2, t3 = 2 * sz3;
        hipLaunchKernelGGL(k_resize, dim3((unsigned)((t1 + TB - 1) / TB)), dim3(TB), 0, stream,
                           left, right, lp1, rp1, B, H, W, H / 2, W / 2);
        hipLaunchKernelGGL(k_resize, dim3((unsigned)((t2 + TB - 1) / TB)), dim3(TB), 0, stream,
                           left, right, lp2, rp2, B, H, W, H / 4, W / 4);
        hipLaunchKernelGGL(k_resize, dim3((unsigned)((t3 + TB - 1) / TB)), dim3(TB), 0, stream,
                           left, right, lp3, rp3, B, H, W, H / 8, W / 8);
    }

    const float* lp[4] = {left, lp1, lp2, lp3};
    const float* rp[4] = {right, rp1, rp2, rp3};
    for (int i = 0; i < 4; ++i) {
        int r = 1 << i;
        int h = H / r, w = W / r;
        long long np = (long long)B * h * w;
        long long ns = (long long)B * (h - 2) * (w - 2);
        float* a = acc + i * 8;
        hipLaunchKernelGGL(k_warp_smooth, dim3((unsigned)((np + TB - 1) / TB)), dim3(TB), 0, stream,
                           disp[i], lp[i], rp[i], a, B, h, w);
        hipLaunchKernelGGL(k_ssim, dim3((unsigned)((ns + TB - 1) / TB)), dim3(TB), 0, stream,
                           disp[i], lp[i], rp[i], a, B, h, w);
    }
    hipLaunchKernelGGL(k_final, dim3(1), dim3(64), 0, stream, acc, out, B, H, W);
}

// Round 3
// 555.167 us; speedup vs baseline: 3.1918x; 3.1918x over previous
//
#include <hip/hip_runtime.h>
#include <math.h>

#define C1F 1.0e-4f   // 0.01^2
#define C2F 9.0e-4f   // 0.03^2
#define TX 32
#define TY 8

// acc layout: per scale i (0..3), base = i*8
//  +0: sum |left_est - lpy|      +1: sum |right_est - rpy|
//  +2: sum |rl_disp - dl|        +3: sum |lr_disp - dr|
//  +4: sum x-grad smooth (dl+dr) +5: sum y-grad smooth (dl+dr)
//  +6: sum ssim_l (clipped)      +7: sum ssim_r

__device__ __forceinline__ void warp_coeffs(float px, int W, int& i0, int& i1,
                                            float& w0, float& w1) {
    float x0f = floorf(px);
    float f = px - x0f;
    int x0i = (int)x0f;
    int x1i = x0i + 1;
    float v0 = (x0i >= 0 && x0i < W) ? 1.f : 0.f;
    float v1 = (x1i >= 0 && x1i < W) ? 1.f : 0.f;
    i0 = min(max(x0i, 0), W - 1);
    i1 = min(max(x1i, 0), W - 1);
    w0 = v0 * (1.f - f);
    w1 = v1 * f;
}

template<int N>
__device__ __forceinline__ void block_acc(const float* vals, float* gacc) {
    __shared__ float sacc[N];
    if (threadIdx.x < N) sacc[threadIdx.x] = 0.f;
    __syncthreads();
#pragma unroll
    for (int k = 0; k < N; ++k) {
        float v = vals[k];
#pragma unroll
        for (int off = 32; off > 0; off >>= 1) v += __shfl_down(v, off, 64);
        if ((threadIdx.x & 63) == 0) atomicAdd(&sacc[k], v);
    }
    __syncthreads();
    if (threadIdx.x < N) atomicAdd(&gacc[threadIdx.x], sacc[threadIdx.x]);
}

__global__ void k_zero(float* acc) {
    if (threadIdx.x < 64) acc[threadIdx.x] = 0.f;
}

// Bilinear align-corners resize of left+right full-res images to (oh, ow).
__global__ void k_resize(const float* __restrict__ left, const float* __restrict__ right,
                         float* __restrict__ lo, float* __restrict__ ro,
                         int B, int H, int W, int oh, int ow) {
    long long idx = (long long)blockIdx.x * blockDim.x + threadIdx.x;
    long long total = (long long)B * 3 * oh * ow;
    if (idx >= 2 * total) return;
    const float* src = left;
    float* dst = lo;
    if (idx >= total) { src = right; dst = ro; idx -= total; }
    int x = (int)(idx % ow);
    long long t = idx / ow;
    int y = (int)(t % oh);
    t /= oh;
    int c = (int)(t % 3);
    int b = (int)(t / 3);
    float sy = (float)(H - 1) / (float)(oh - 1);
    float sx = (float)(W - 1) / (float)(ow - 1);
    float fy = y * sy;
    float fx = x * sx;
    int y0 = (int)floorf(fy); float wy = fy - (float)y0;
    int x0 = (int)floorf(fx); float wx = fx - (float)x0;
    int y1 = min(y0 + 1, H - 1); y0 = min(y0, H - 1);
    int x1 = min(x0 + 1, W - 1); x0 = min(x0, W - 1);
    const float* p = src + (((long long)b * 3 + c) * H) * W;
    float a00 = p[(long long)y0 * W + x0];
    float a10 = p[(long long)y1 * W + x0];
    float a01 = p[(long long)y0 * W + x1];
    float a11 = p[(long long)y1 * W + x1];
    float r0 = a00 * (1.f - wy) + a10 * wy;
    float r1 = a01 * (1.f - wy) + a11 * wy;
    dst[(((long long)b * 3 + c) * oh + y) * ow + x] = r0 * (1.f - wx) + r1 * wx;
}

// Fully fused per-scale loss kernel.
// Stage (le,lv,re,rv) per channel + (dl,dr) into LDS for a (TX+2)x(TY+2)
// halo tile, then compute L1 / LR / smoothness / SSIM from LDS.
// Each warp gather is computed ONCE per pixel (R1/R2 recomputed them up to
// 27x in registers -> 0.6-1.1 GB of scratch spill traffic).
__global__ void __launch_bounds__(256, 4)
k_fused(const float* __restrict__ disp, const float* __restrict__ lpy,
        const float* __restrict__ rpy, float* __restrict__ acc,
        int B, int h, int w) {
    __shared__ float4 simg[3][(TY + 2) * (TX + 2)];
    __shared__ float2 sdisp[(TY + 2) * (TX + 2)];

    const int b = blockIdx.z;
    const int xo0 = blockIdx.x * TX;
    const int yo0 = blockIdx.y * TY;
    const int tid = threadIdx.x;
    const float Wm1 = (float)(w - 1);
    const float invWm1 = 1.f / Wm1;

    const float* dl_base = disp + ((long long)b * 2 + 0) * h * w;
    const float* dr_base = disp + ((long long)b * 2 + 1) * h * w;

    // ---- staging: one warp-gather per pixel, results go to LDS ----
    for (int i = tid; i < (TY + 2) * (TX + 2); i += 256) {
        int sx = i % (TX + 2);
        int sy = i / (TX + 2);
        int x = min(max(xo0 - 1 + sx, 0), w - 1);
        int y = min(max(yo0 - 1 + sy, 0), h - 1);
        const float* dl_row = dl_base + (long long)y * w;
        const float* dr_row = dr_base + (long long)y * w;
        float dl = dl_row[x], dr = dr_row[x];
        sdisp[i] = make_float2(dl, dr);
        float xb = (float)x * invWm1;
        int i0L, i1L; float w0L, w1L;
        warp_coeffs((xb - dl) * Wm1, w, i0L, i1L, w0L, w1L);
        int i0R, i1R; float w0R, w1R;
        warp_coeffs((xb + dr) * Wm1, w, i0R, i1R, w0R, w1R);
#pragma unroll
        for (int c = 0; c < 3; ++c) {
            const float* lrow = lpy + (((long long)b * 3 + c) * h + y) * w;
            const float* rrow = rpy + (((long long)b * 3 + c) * h + y) * w;
            float lv = lrow[x], rv = rrow[x];
            float le = rrow[i0L] * w0L + rrow[i1L] * w1L;
            float re = lrow[i0R] * w0R + lrow[i1R] * w1R;
            simg[c][i] = make_float4(le, lv, re, rv);
        }
    }
    __syncthreads();

    float sums[8] = {0.f, 0.f, 0.f, 0.f, 0.f, 0.f, 0.f, 0.f};
    const int tx = tid % TX, ty = tid / TX;
    const int x = xo0 + tx, y = yo0 + ty;
    if (x < w && y < h) {
        const int s = (ty + 1) * (TX + 2) + (tx + 1);   // own pixel's slot
        float2 dd = sdisp[s];
        float dl = dd.x, dr = dd.y;
        // L1 photometric
#pragma unroll
        for (int c = 0; c < 3; ++c) {
            float4 v = simg[c][s];
            sums[0] += fabsf(v.x - v.y);
            sums[1] += fabsf(v.z - v.w);
        }
        // LR consistency (needs far gathers on disp rows -> global)
        {
            float xb = (float)x * invWm1;
            int i0, i1; float w0, w1;
            warp_coeffs((xb - dl) * Wm1, w, i0, i1, w0, w1);
            const float* dr_row = dr_base + (long long)y * w;
            float rl = dr_row[i0] * w0 + dr_row[i1] * w1;
            sums[2] += fabsf(rl - dl);
            warp_coeffs((xb + dr) * Wm1, w, i0, i1, w0, w1);
            const float* dl_row = dl_base + (long long)y * w;
            float lr = dl_row[i0] * w0 + dl_row[i1] * w1;
            sums[3] += fabsf(lr - dr);
        }
        // edge-aware smoothness (neighbors from LDS)
        const float third = 1.f / 3.f;
        if (x < w - 1) {
            float2 d1 = sdisp[s + 1];
            float al = 0.f, ar = 0.f;
#pragma unroll
            for (int c = 0; c < 3; ++c) {
                float4 v = simg[c][s];
                float4 v1 = simg[c][s + 1];
                al += fabsf(v.y - v1.y);
                ar += fabsf(v.w - v1.w);
            }
            sums[4] += fabsf((dl - d1.x) * expf(-al * third)) +
                       fabsf((dr - d1.y) * expf(-ar * third));
        }
        if (y < h - 1) {
            float2 d1 = sdisp[s + (TX + 2)];
            float al = 0.f, ar = 0.f;
#pragma unroll
            for (int c = 0; c < 3; ++c) {
                float4 v = simg[c][s];
                float4 v1 = simg[c][s + (TX + 2)];
                al += fabsf(v.y - v1.y);
                ar += fabsf(v.w - v1.w);
            }
            sums[5] += fabsf((dl - d1.x) * expf(-al * third)) +
                       fabsf((dr - d1.y) * expf(-ar * third));
        }
        // SSIM, window centered at (x,y); valid centers 1..w-2 / 1..h-2
        if (x >= 1 && x <= w - 2 && y >= 1 && y <= h - 2) {
            const float inv9 = 1.f / 9.f;
#pragma unroll 1
            for (int c = 0; c < 3; ++c) {
                float sLx = 0.f, sLy = 0.f, sLxx = 0.f, sLyy = 0.f, sLxy = 0.f;
                float sRx = 0.f, sRy = 0.f, sRxx = 0.f, sRyy = 0.f, sRxy = 0.f;
#pragma unroll
                for (int dy = 0; dy < 3; ++dy) {
#pragma unroll
                    for (int dx = 0; dx < 3; ++dx) {
                        float4 v = simg[c][(ty + dy) * (TX + 2) + (tx + dx)];
                        sLx += v.x; sLy += v.y;
                        sLxx += v.x * v.x; sLyy += v.y * v.y; sLxy += v.x * v.y;
                        sRx += v.z; sRy += v.w;
                        sRxx += v.z * v.z; sRyy += v.w * v.w; sRxy += v.z * v.w;
                    }
                }
                {
                    float mx = sLx * inv9, my = sLy * inv9;
                    float vx = sLxx * inv9 - mx * mx;
                    float vy = sLyy * inv9 - my * my;
                    float vxy = sLxy * inv9 - mx * my;
                    float ss = (2.f * mx * my + C1F) * (2.f * vxy + C2F) /
                               ((mx * mx + my * my + C1F) * (vx + vy + C2F));
                    float v = (1.f - ss) * 0.5f;
                    sums[6] += fminf(fmaxf(v, 0.f), 1.f);
                }
                {
                    float mx = sRx * inv9, my = sRy * inv9;
                    float vx = sRxx * inv9 - mx * mx;
                    float vy = sRyy * inv9 - my * my;
                    float vxy = sRxy * inv9 - mx * my;
                    float ss = (2.f * mx * my + C1F) * (2.f * vxy + C2F) /
                               ((mx * mx + my * my + C1F) * (vx + vy + C2F));
                    float v = (1.f - ss) * 0.5f;
                    sums[7] += fminf(fmaxf(v, 0.f), 1.f);
                }
            }
        }
    }
    block_acc<8>(sums, acc);
}

__global__ void k_final(const float* __restrict__ acc, float* __restrict__ out,
                        int B, int H, int W) {
    if (threadIdx.x != 0 || blockIdx.x != 0) return;
    float img = 0.f, lr = 0.f, sm = 0.f;
    for (int i = 0; i < 4; ++i) {
        int r = 1 << i;
        int h = H / r, w = W / r;
        const float* a = acc + i * 8;
        float Nl1 = (float)B * 3.f * (float)h * (float)w;
        float Nss = (float)B * 3.f * (float)(h - 2) * (float)(w - 2);
        float Nlr = (float)B * (float)h * (float)w;
        float Nsx = (float)B * (float)h * (float)(w - 1);
        float Nsy = (float)B * (float)(h - 1) * (float)w;
        img += 0.5f * (a[6] / Nss) + 0.5f * (a[0] / Nl1)
             + 0.5f * (a[7] / Nss) + 0.5f * (a[1] / Nl1);
        lr += a[2] / Nlr + a[3] / Nlr;
        sm += (a[4] / Nsx + a[5] / Nsy) / (float)r;
    }
    out[0] = img + 0.1f * sm + 1.0f * lr;
}

extern "C" void kernel_launch(void* const* d_in, const int* in_sizes, int n_in,
                              void* d_out, int out_size, void* d_ws, size_t ws_size,
                              hipStream_t stream) {
    const int B = 16, H = 384, W = 768;
    const float* disp[4] = {(const float*)d_in[0], (const float*)d_in[1],
                            (const float*)d_in[2], (const float*)d_in[3]};
    const float* left = (const float*)d_in[4];
    const float* right = (const float*)d_in[5];
    float* out = (float*)d_out;

    float* acc = (float*)d_ws;
    float* pyr = acc + 256;
    long long sz1 = (long long)B * 3 * (H / 2) * (W / 2);
    long long sz2 = (long long)B * 3 * (H / 4) * (W / 4);
    long long sz3 = (long long)B * 3 * (H / 8) * (W / 8);
    float* lp1 = pyr;
    float* rp1 = lp1 + sz1;
    float* lp2 = rp1 + sz1;
    float* rp2 = lp2 + sz2;
    float* lp3 = rp2 + sz2;
    float* rp3 = lp3 + sz3;

    const int TB = 256;
    hipLaunchKernelGGL(k_zero, dim3(1), dim3(64), 0, stream, acc);

    {
        long long t1 = 2 * sz1, t2 = 2 * sz2, t3 = 2 * sz3;
        hipLaunchKernelGGL(k_resize, dim3((unsigned)((t1 + TB - 1) / TB)), dim3(TB), 0, stream,
                           left, right, lp1, rp1, B, H, W, H / 2, W / 2);
        hipLaunchKernelGGL(k_resize, dim3((unsigned)((t2 + TB - 1) / TB)), dim3(TB), 0, stream,
                           left, right, lp2, rp2, B, H, W, H / 4, W / 4);
        hipLaunchKernelGGL(k_resize, dim3((unsigned)((t3 + TB - 1) / TB)), dim3(TB), 0, stream,
                           left, right, lp3, rp3, B, H, W, H / 8, W / 8);
    }

    const float* lp[4] = {left, lp1, lp2, lp3};
    const float* rp[4] = {right, rp1, rp2, rp3};
    for (int i = 0; i < 4; ++i) {
        int r = 1 << i;
        int h = H / r, w = W / r;
        dim3 grid((unsigned)((w + TX - 1) / TX), (unsigned)((h + TY - 1) / TY), B);
        hipLaunchKernelGGL(k_fused, grid, dim3(TB), 0, stream,
                           disp[i], lp[i], rp[i], acc + i * 8, B, h, w);
    }
    hipLaunchKernelGGL(k_final, dim3(1), dim3(64), 0, stream, acc, out, B, H, W);
}

// Round 4
// 518.534 us; speedup vs baseline: 3.4173x; 1.0706x over previous
//
#include <hip/hip_runtime.h>
#include <math.h>

#define C1F 1.0e-4f   // 0.01^2
#define C2F 9.0e-4f   // 0.03^2
#define TX 32
#define TY 8

// acc layout: per scale i (0..3), base = i*8
//  +0: sum |left_est - lpy|      +1: sum |right_est - rpy|
//  +2: sum |rl_disp - dl|        +3: sum |lr_disp - dr|
//  +4: sum x-grad smooth (dl+dr) +5: sum y-grad smooth (dl+dr)
//  +6: sum ssim_l (clipped)      +7: sum ssim_r

struct ScaleArgs {
    const float* disp;
    const float* lp;
    const float* rp;
    int h, w, nx, ny, blk0;
};

__device__ __forceinline__ void warp_coeffs(float px, int W, int& i0, int& i1,
                                            float& w0, float& w1) {
    float x0f = floorf(px);
    float f = px - x0f;
    int x0i = (int)x0f;
    int x1i = x0i + 1;
    float v0 = (x0i >= 0 && x0i < W) ? 1.f : 0.f;
    float v1 = (x1i >= 0 && x1i < W) ? 1.f : 0.f;
    i0 = min(max(x0i, 0), W - 1);
    i1 = min(max(x1i, 0), W - 1);
    w0 = v0 * (1.f - f);
    w1 = v1 * f;
}

template<int N>
__device__ __forceinline__ void block_acc(const float* vals, float* gacc) {
    __shared__ float sacc[N];
    if (threadIdx.x < N) sacc[threadIdx.x] = 0.f;
    __syncthreads();
#pragma unroll
    for (int k = 0; k < N; ++k) {
        float v = vals[k];
#pragma unroll
        for (int off = 32; off > 0; off >>= 1) v += __shfl_down(v, off, 64);
        if ((threadIdx.x & 63) == 0) atomicAdd(&sacc[k], v);
    }
    __syncthreads();
    if (threadIdx.x < N) atomicAdd(&gacc[threadIdx.x], sacc[threadIdx.x]);
}

// Bilinear align-corners resize of left+right to all three pyramid levels,
// one launch. Last block also zeroes the accumulator (replaces k_zero; safe:
// nothing else in this kernel touches acc, and the fused kernel runs after).
__global__ void __launch_bounds__(256, 4)
k_resize_all(const float* __restrict__ left, const float* __restrict__ right,
             float* __restrict__ lo1, float* __restrict__ ro1,
             float* __restrict__ lo2, float* __restrict__ ro2,
             float* __restrict__ lo3, float* __restrict__ ro3,
             float* __restrict__ acc,
             int B, int H, int W,
             long long n1, long long n2, long long n3) {
    if (blockIdx.x == gridDim.x - 1 && threadIdx.x < 64) acc[threadIdx.x] = 0.f;
    long long idx = (long long)blockIdx.x * blockDim.x + threadIdx.x;
    int oh, ow;
    float* lo;
    float* ro;
    if (idx < n1) {
        oh = H / 2; ow = W / 2; lo = lo1; ro = ro1;
    } else if (idx < n1 + n2) {
        idx -= n1; oh = H / 4; ow = W / 4; lo = lo2; ro = ro2;
    } else if (idx < n1 + n2 + n3) {
        idx -= n1 + n2; oh = H / 8; ow = W / 8; lo = lo3; ro = ro3;
    } else {
        return;
    }
    long long half = (long long)B * 3 * oh * ow;
    const float* src = left;
    float* dst = lo;
    if (idx >= half) { src = right; dst = ro; idx -= half; }
    int x = (int)(idx % ow);
    long long t = idx / ow;
    int y = (int)(t % oh);
    t /= oh;
    int c = (int)(t % 3);
    int b = (int)(t / 3);
    float sy = (float)(H - 1) / (float)(oh - 1);
    float sx = (float)(W - 1) / (float)(ow - 1);
    float fy = y * sy;
    float fx = x * sx;
    int y0 = (int)floorf(fy); float wy = fy - (float)y0;
    int x0 = (int)floorf(fx); float wx = fx - (float)x0;
    int y1 = min(y0 + 1, H - 1); y0 = min(y0, H - 1);
    int x1 = min(x0 + 1, W - 1); x0 = min(x0, W - 1);
    const float* p = src + (((long long)b * 3 + c) * H) * W;
    float a00 = p[(long long)y0 * W + x0];
    float a10 = p[(long long)y1 * W + x0];
    float a01 = p[(long long)y0 * W + x1];
    float a11 = p[(long long)y1 * W + x1];
    float r0 = a00 * (1.f - wy) + a10 * wy;
    float r1 = a01 * (1.f - wy) + a11 * wy;
    dst[(((long long)b * 3 + c) * oh + y) * ow + x] = r0 * (1.f - wx) + r1 * wx;
}

// Fully fused loss kernel, ALL 4 SCALES in one launch. Scale-0 tiles first,
// small scales last so they fill the drain tail. Per-block everything is
// wave-uniform; per-pixel math identical to R3 (absmax was 0.0).
__global__ void __launch_bounds__(256, 4)
k_fused_all(ScaleArgs s0, ScaleArgs s1, ScaleArgs s2, ScaleArgs s3,
            float* __restrict__ accbase) {
    __shared__ float4 simg[3][(TY + 2) * (TX + 2)];
    __shared__ float2 sdisp[(TY + 2) * (TX + 2)];

    ScaleArgs sa;
    int scale;
    {
        int blk = blockIdx.x;
        if (blk >= s3.blk0)      { sa = s3; scale = 3; }
        else if (blk >= s2.blk0) { sa = s2; scale = 2; }
        else if (blk >= s1.blk0) { sa = s1; scale = 1; }
        else                     { sa = s0; scale = 0; }
    }
    const int h = sa.h, w = sa.w;
    const float* __restrict__ disp = sa.disp;
    const float* __restrict__ lpy = sa.lp;
    const float* __restrict__ rpy = sa.rp;
    float* acc = accbase + scale * 8;

    int t = blockIdx.x - sa.blk0;
    const int tileX = t % sa.nx;
    int t2 = t / sa.nx;
    const int tileY = t2 % sa.ny;
    const int b = t2 / sa.ny;

    const int xo0 = tileX * TX;
    const int yo0 = tileY * TY;
    const int tid = threadIdx.x;
    const float Wm1 = (float)(w - 1);
    const float invWm1 = 1.f / Wm1;

    const float* dl_base = disp + ((long long)b * 2 + 0) * h * w;
    const float* dr_base = disp + ((long long)b * 2 + 1) * h * w;

    // ---- staging: one warp-gather per pixel, results go to LDS ----
    for (int i = tid; i < (TY + 2) * (TX + 2); i += 256) {
        int sx = i % (TX + 2);
        int sy = i / (TX + 2);
        int x = min(max(xo0 - 1 + sx, 0), w - 1);
        int y = min(max(yo0 - 1 + sy, 0), h - 1);
        const float* dl_row = dl_base + (long long)y * w;
        const float* dr_row = dr_base + (long long)y * w;
        float dl = dl_row[x], dr = dr_row[x];
        sdisp[i] = make_float2(dl, dr);
        float xb = (float)x * invWm1;
        int i0L, i1L; float w0L, w1L;
        warp_coeffs((xb - dl) * Wm1, w, i0L, i1L, w0L, w1L);
        int i0R, i1R; float w0R, w1R;
        warp_coeffs((xb + dr) * Wm1, w, i0R, i1R, w0R, w1R);
#pragma unroll
        for (int c = 0; c < 3; ++c) {
            const float* lrow = lpy + (((long long)b * 3 + c) * h + y) * w;
            const float* rrow = rpy + (((long long)b * 3 + c) * h + y) * w;
            float lv = lrow[x], rv = rrow[x];
            float le = rrow[i0L] * w0L + rrow[i1L] * w1L;
            float re = lrow[i0R] * w0R + lrow[i1R] * w1R;
            simg[c][i] = make_float4(le, lv, re, rv);
        }
    }
    __syncthreads();

    float sums[8] = {0.f, 0.f, 0.f, 0.f, 0.f, 0.f, 0.f, 0.f};
    const int tx = tid % TX, ty = tid / TX;
    const int x = xo0 + tx, y = yo0 + ty;
    if (x < w && y < h) {
        const int s = (ty + 1) * (TX + 2) + (tx + 1);   // own pixel's slot
        float2 dd = sdisp[s];
        float dl = dd.x, dr = dd.y;
        // L1 photometric
#pragma unroll
        for (int c = 0; c < 3; ++c) {
            float4 v = simg[c][s];
            sums[0] += fabsf(v.x - v.y);
            sums[1] += fabsf(v.z - v.w);
        }
        // LR consistency (far gathers on disp rows -> global)
        {
            float xb = (float)x * invWm1;
            int i0, i1; float w0, w1;
            warp_coeffs((xb - dl) * Wm1, w, i0, i1, w0, w1);
            const float* dr_row = dr_base + (long long)y * w;
            float rl = dr_row[i0] * w0 + dr_row[i1] * w1;
            sums[2] += fabsf(rl - dl);
            warp_coeffs((xb + dr) * Wm1, w, i0, i1, w0, w1);
            const float* dl_row = dl_base + (long long)y * w;
            float lr = dl_row[i0] * w0 + dl_row[i1] * w1;
            sums[3] += fabsf(lr - dr);
        }
        // edge-aware smoothness (neighbors from LDS)
        const float third = 1.f / 3.f;
        if (x < w - 1) {
            float2 d1 = sdisp[s + 1];
            float al = 0.f, ar = 0.f;
#pragma unroll
            for (int c = 0; c < 3; ++c) {
                float4 v = simg[c][s];
                float4 v1 = simg[c][s + 1];
                al += fabsf(v.y - v1.y);
                ar += fabsf(v.w - v1.w);
            }
            sums[4] += fabsf((dl - d1.x) * expf(-al * third)) +
                       fabsf((dr - d1.y) * expf(-ar * third));
        }
        if (y < h - 1) {
            float2 d1 = sdisp[s + (TX + 2)];
            float al = 0.f, ar = 0.f;
#pragma unroll
            for (int c = 0; c < 3; ++c) {
                float4 v = simg[c][s];
                float4 v1 = simg[c][s + (TX + 2)];
                al += fabsf(v.y - v1.y);
                ar += fabsf(v.w - v1.w);
            }
            sums[5] += fabsf((dl - d1.x) * expf(-al * third)) +
                       fabsf((dr - d1.y) * expf(-ar * third));
        }
        // SSIM, window centered at (x,y); valid centers 1..w-2 / 1..h-2
        if (x >= 1 && x <= w - 2 && y >= 1 && y <= h - 2) {
            const float inv9 = 1.f / 9.f;
#pragma unroll 1
            for (int c = 0; c < 3; ++c) {
                float sLx = 0.f, sLy = 0.f, sLxx = 0.f, sLyy = 0.f, sLxy = 0.f;
                float sRx = 0.f, sRy = 0.f, sRxx = 0.f, sRyy = 0.f, sRxy = 0.f;
#pragma unroll
                for (int dy = 0; dy < 3; ++dy) {
#pragma unroll
                    for (int dx = 0; dx < 3; ++dx) {
                        float4 v = simg[c][(ty + dy) * (TX + 2) + (tx + dx)];
                        sLx += v.x; sLy += v.y;
                        sLxx += v.x * v.x; sLyy += v.y * v.y; sLxy += v.x * v.y;
                        sRx += v.z; sRy += v.w;
                        sRxx += v.z * v.z; sRyy += v.w * v.w; sRxy += v.z * v.w;
                    }
                }
                {
                    float mx = sLx * inv9, my = sLy * inv9;
                    float vx = sLxx * inv9 - mx * mx;
                    float vy = sLyy * inv9 - my * my;
                    float vxy = sLxy * inv9 - mx * my;
                    float ss = (2.f * mx * my + C1F) * (2.f * vxy + C2F) /
                               ((mx * mx + my * my + C1F) * (vx + vy + C2F));
                    float v = (1.f - ss) * 0.5f;
                    sums[6] += fminf(fmaxf(v, 0.f), 1.f);
                }
                {
                    float mx = sRx * inv9, my = sRy * inv9;
                    float vx = sRxx * inv9 - mx * mx;
                    float vy = sRyy * inv9 - my * my;
                    float vxy = sRxy * inv9 - mx * my;
                    float ss = (2.f * mx * my + C1F) * (2.f * vxy + C2F) /
                               ((mx * mx + my * my + C1F) * (vx + vy + C2F));
                    float v = (1.f - ss) * 0.5f;
                    sums[7] += fminf(fmaxf(v, 0.f), 1.f);
                }
            }
        }
    }
    block_acc<8>(sums, acc);
}

__global__ void k_final(const float* __restrict__ acc, float* __restrict__ out,
                        int B, int H, int W) {
    if (threadIdx.x != 0 || blockIdx.x != 0) return;
    float img = 0.f, lr = 0.f, sm = 0.f;
    for (int i = 0; i < 4; ++i) {
        int r = 1 << i;
        int h = H / r, w = W / r;
        const float* a = acc + i * 8;
        float Nl1 = (float)B * 3.f * (float)h * (float)w;
        float Nss = (float)B * 3.f * (float)(h - 2) * (float)(w - 2);
        float Nlr = (float)B * (float)h * (float)w;
        float Nsx = (float)B * (float)h * (float)(w - 1);
        float Nsy = (float)B * (float)(h - 1) * (float)w;
        img += 0.5f * (a[6] / Nss) + 0.5f * (a[0] / Nl1)
             + 0.5f * (a[7] / Nss) + 0.5f * (a[1] / Nl1);
        lr += a[2] / Nlr + a[3] / Nlr;
        sm += (a[4] / Nsx + a[5] / Nsy) / (float)r;
    }
    out[0] = img + 0.1f * sm + 1.0f * lr;
}

extern "C" void kernel_launch(void* const* d_in, const int* in_sizes, int n_in,
                              void* d_out, int out_size, void* d_ws, size_t ws_size,
                              hipStream_t stream) {
    const int B = 16, H = 384, W = 768;
    const float* disp[4] = {(const float*)d_in[0], (const float*)d_in[1],
                            (const float*)d_in[2], (const float*)d_in[3]};
    const float* left = (const float*)d_in[4];
    const float* right = (const float*)d_in[5];
    float* out = (float*)d_out;

    float* acc = (float*)d_ws;
    float* pyr = acc + 256;
    long long sz1 = (long long)B * 3 * (H / 2) * (W / 2);
    long long sz2 = (long long)B * 3 * (H / 4) * (W / 4);
    long long sz3 = (long long)B * 3 * (H / 8) * (W / 8);
    float* lp1 = pyr;
    float* rp1 = lp1 + sz1;
    float* lp2 = rp1 + sz1;
    float* rp2 = lp2 + sz2;
    float* lp3 = rp2 + sz2;
    float* rp3 = lp3 + sz3;

    const int TB = 256;

    // one resize kernel for all pyramid levels (+ acc zeroing)
    {
        long long n1 = 2 * sz1, n2 = 2 * sz2, n3 = 2 * sz3;
        long long nt = n1 + n2 + n3;
        hipLaunchKernelGGL(k_resize_all, dim3((unsigned)((nt + TB - 1) / TB)), dim3(TB), 0, stream,
                           left, right, lp1, rp1, lp2, rp2, lp3, rp3, acc,
                           B, H, W, n1, n2, n3);
    }

    // one fused kernel for all 4 scales
    {
        const float* lp[4] = {left, lp1, lp2, lp3};
        const float* rp[4] = {right, rp1, rp2, rp3};
        ScaleArgs sa[4];
        int blk0 = 0;
        for (int i = 0; i < 4; ++i) {
            int r = 1 << i;
            int h = H / r, w = W / r;
            sa[i].disp = disp[i];
            sa[i].lp = lp[i];
            sa[i].rp = rp[i];
            sa[i].h = h;
            sa[i].w = w;
            sa[i].nx = w / TX;
            sa[i].ny = h / TY;
            sa[i].blk0 = blk0;
            blk0 += sa[i].nx * sa[i].ny * B;
        }
        hipLaunchKernelGGL(k_fused_all, dim3((unsigned)blk0), dim3(TB), 0, stream,
                           sa[0], sa[1], sa[2], sa[3], acc);
    }
    hipLaunchKernelGGL(k_final, dim3(1), dim3(64), 0, stream, acc, out, B, H, W);
}

// Round 5
// 505.954 us; speedup vs baseline: 3.5023x; 1.0249x over previous
//
#include <hip/hip_runtime.h>
#include <math.h>

#define C1F 1.0e-4f   // 0.01^2
#define C2F 9.0e-4f   // 0.03^2
#define TX 32
#define TY 8

// acc layout: per scale i (0..3), base = i*8
//  +0: sum |left_est - lpy|      +1: sum |right_est - rpy|
//  +2: sum |rl_disp - dl|        +3: sum |lr_disp - dr|
//  +4: sum x-grad smooth (dl+dr) +5: sum y-grad smooth (dl+dr)
//  +6: sum ssim_l (clipped)      +7: sum ssim_r

struct ScaleArgs {
    const float* disp;
    const float* lp;
    const float* rp;
    int h, w, nx, ny, blk0;
};

__device__ __forceinline__ float2 f2(float v) { return make_float2(v, v); }
__device__ __forceinline__ float2 f2abs(float2 a) {
    return make_float2(fabsf(a.x), fabsf(a.y));
}

__device__ __forceinline__ void warp_coeffs(float px, int W, int& i0, int& i1,
                                            float& w0, float& w1) {
    float x0f = floorf(px);
    float f = px - x0f;
    int x0i = (int)x0f;
    int x1i = x0i + 1;
    float v0 = (x0i >= 0 && x0i < W) ? 1.f : 0.f;
    float v1 = (x1i >= 0 && x1i < W) ? 1.f : 0.f;
    i0 = min(max(x0i, 0), W - 1);
    i1 = min(max(x1i, 0), W - 1);
    w0 = v0 * (1.f - f);
    w1 = v1 * f;
}

template<int N>
__device__ __forceinline__ void block_acc(const float* vals, float* gacc) {
    __shared__ float sacc[N];
    if (threadIdx.x < N) sacc[threadIdx.x] = 0.f;
    __syncthreads();
#pragma unroll
    for (int k = 0; k < N; ++k) {
        float v = vals[k];
#pragma unroll
        for (int off = 32; off > 0; off >>= 1) v += __shfl_down(v, off, 64);
        if ((threadIdx.x & 63) == 0) atomicAdd(&sacc[k], v);
    }
    __syncthreads();
    if (threadIdx.x < N) atomicAdd(&gacc[threadIdx.x], sacc[threadIdx.x]);
}

// Bilinear align-corners resize of left+right to all three pyramid levels,
// one launch. Last block also zeroes the accumulator.
__global__ void __launch_bounds__(256, 4)
k_resize_all(const float* __restrict__ left, const float* __restrict__ right,
             float* __restrict__ lo1, float* __restrict__ ro1,
             float* __restrict__ lo2, float* __restrict__ ro2,
             float* __restrict__ lo3, float* __restrict__ ro3,
             float* __restrict__ acc,
             int B, int H, int W,
             long long n1, long long n2, long long n3) {
    if (blockIdx.x == gridDim.x - 1 && threadIdx.x < 64) acc[threadIdx.x] = 0.f;
    long long idx = (long long)blockIdx.x * blockDim.x + threadIdx.x;
    int oh, ow;
    float* lo;
    float* ro;
    if (idx < n1) {
        oh = H / 2; ow = W / 2; lo = lo1; ro = ro1;
    } else if (idx < n1 + n2) {
        idx -= n1; oh = H / 4; ow = W / 4; lo = lo2; ro = ro2;
    } else if (idx < n1 + n2 + n3) {
        idx -= n1 + n2; oh = H / 8; ow = W / 8; lo = lo3; ro = ro3;
    } else {
        return;
    }
    long long half = (long long)B * 3 * oh * ow;
    const float* src = left;
    float* dst = lo;
    if (idx >= half) { src = right; dst = ro; idx -= half; }
    int x = (int)(idx % ow);
    long long t = idx / ow;
    int y = (int)(t % oh);
    t /= oh;
    int c = (int)(t % 3);
    int b = (int)(t / 3);
    float sy = (float)(H - 1) / (float)(oh - 1);
    float sx = (float)(W - 1) / (float)(ow - 1);
    float fy = y * sy;
    float fx = x * sx;
    int y0 = (int)floorf(fy); float wy = fy - (float)y0;
    int x0 = (int)floorf(fx); float wx = fx - (float)x0;
    int y1 = min(y0 + 1, H - 1); y0 = min(y0, H - 1);
    int x1 = min(x0 + 1, W - 1); x0 = min(x0, W - 1);
    const float* p = src + (((long long)b * 3 + c) * H) * W;
    float a00 = p[(long long)y0 * W + x0];
    float a10 = p[(long long)y1 * W + x0];
    float a01 = p[(long long)y0 * W + x1];
    float a11 = p[(long long)y1 * W + x1];
    float r0 = a00 * (1.f - wy) + a10 * wy;
    float r1 = a01 * (1.f - wy) + a11 * wy;
    dst[(((long long)b * 3 + c) * oh + y) * ow + x] = r0 * (1.f - wx) + r1 * wx;
}

// Fully fused loss kernel, all 4 scales in one launch.
// LDS tile layout is (le, re, lv, rv) so the L/R sides land in aligned VGPR
// pairs -> float2 arithmetic compiles to VOP3P packed fp32 (v_pk_fma_f32),
// halving the SSIM window-loop VALU count vs R4.
__global__ void __launch_bounds__(256, 4)
k_fused_all(ScaleArgs s0, ScaleArgs s1, ScaleArgs s2, ScaleArgs s3,
            float* __restrict__ accbase) {
    __shared__ float4 simg[3][(TY + 2) * (TX + 2)];
    __shared__ float2 sdisp[(TY + 2) * (TX + 2)];

    ScaleArgs sa;
    int scale;
    {
        int blk = blockIdx.x;
        if (blk >= s3.blk0)      { sa = s3; scale = 3; }
        else if (blk >= s2.blk0) { sa = s2; scale = 2; }
        else if (blk >= s1.blk0) { sa = s1; scale = 1; }
        else                     { sa = s0; scale = 0; }
    }
    const int h = sa.h, w = sa.w;
    const float* __restrict__ disp = sa.disp;
    const float* __restrict__ lpy = sa.lp;
    const float* __restrict__ rpy = sa.rp;
    float* acc = accbase + scale * 8;

    int t = blockIdx.x - sa.blk0;
    const int tileX = t % sa.nx;
    int t2 = t / sa.nx;
    const int tileY = t2 % sa.ny;
    const int b = t2 / sa.ny;

    const int xo0 = tileX * TX;
    const int yo0 = tileY * TY;
    const int tid = threadIdx.x;
    const float Wm1 = (float)(w - 1);
    const float invWm1 = 1.f / Wm1;

    const float* dl_base = disp + ((long long)b * 2 + 0) * h * w;
    const float* dr_base = disp + ((long long)b * 2 + 1) * h * w;

    // ---- staging: one warp-gather per pixel, results go to LDS ----
    for (int i = tid; i < (TY + 2) * (TX + 2); i += 256) {
        int sx = i % (TX + 2);
        int sy = i / (TX + 2);
        int x = min(max(xo0 - 1 + sx, 0), w - 1);
        int y = min(max(yo0 - 1 + sy, 0), h - 1);
        const float* dl_row = dl_base + (long long)y * w;
        const float* dr_row = dr_base + (long long)y * w;
        float dl = dl_row[x], dr = dr_row[x];
        sdisp[i] = make_float2(dl, dr);
        float xb = (float)x * invWm1;
        int i0L, i1L; float w0L, w1L;
        warp_coeffs((xb - dl) * Wm1, w, i0L, i1L, w0L, w1L);
        int i0R, i1R; float w0R, w1R;
        warp_coeffs((xb + dr) * Wm1, w, i0R, i1R, w0R, w1R);
#pragma unroll
        for (int c = 0; c < 3; ++c) {
            const float* lrow = lpy + (((long long)b * 3 + c) * h + y) * w;
            const float* rrow = rpy + (((long long)b * 3 + c) * h + y) * w;
            float lv = lrow[x], rv = rrow[x];
            float le = rrow[i0L] * w0L + rrow[i1L] * w1L;
            float re = lrow[i0R] * w0R + lrow[i1R] * w1R;
            simg[c][i] = make_float4(le, re, lv, rv);   // (est_pair, val_pair)
        }
    }
    __syncthreads();

    float sums[8] = {0.f, 0.f, 0.f, 0.f, 0.f, 0.f, 0.f, 0.f};
    const int tx = tid % TX, ty = tid / TX;
    const int x = xo0 + tx, y = yo0 + ty;
    if (x < w && y < h) {
        const int s = (ty + 1) * (TX + 2) + (tx + 1);   // own pixel's slot
        float2 dd = sdisp[s];
        float dl = dd.x, dr = dd.y;
        // L1 photometric (packed)
#pragma unroll
        for (int c = 0; c < 3; ++c) {
            float4 v = simg[c][s];
            float2 a = make_float2(v.x, v.y);   // (le, re)
            float2 bb = make_float2(v.z, v.w);  // (lv, rv)
            float2 d = f2abs(a - bb);
            sums[0] += d.x;
            sums[1] += d.y;
        }
        // LR consistency (far gathers on disp rows -> global)
        {
            float xb = (float)x * invWm1;
            int i0, i1; float w0, w1;
            warp_coeffs((xb - dl) * Wm1, w, i0, i1, w0, w1);
            const float* dr_row = dr_base + (long long)y * w;
            float rl = dr_row[i0] * w0 + dr_row[i1] * w1;
            sums[2] += fabsf(rl - dl);
            warp_coeffs((xb + dr) * Wm1, w, i0, i1, w0, w1);
            const float* dl_row = dl_base + (long long)y * w;
            float lr = dl_row[i0] * w0 + dl_row[i1] * w1;
            sums[3] += fabsf(lr - dr);
        }
        // edge-aware smoothness (neighbors from LDS)
        const float third = 1.f / 3.f;
        if (x < w - 1) {
            float2 d1 = sdisp[s + 1];
            float2 alr = f2(0.f);
#pragma unroll
            for (int c = 0; c < 3; ++c) {
                float4 v = simg[c][s];
                float4 v1 = simg[c][s + 1];
                alr = alr + f2abs(make_float2(v.z, v.w) - make_float2(v1.z, v1.w));
            }
            sums[4] += fabsf((dl - d1.x) * expf(-alr.x * third)) +
                       fabsf((dr - d1.y) * expf(-alr.y * third));
        }
        if (y < h - 1) {
            float2 d1 = sdisp[s + (TX + 2)];
            float2 alr = f2(0.f);
#pragma unroll
            for (int c = 0; c < 3; ++c) {
                float4 v = simg[c][s];
                float4 v1 = simg[c][s + (TX + 2)];
                alr = alr + f2abs(make_float2(v.z, v.w) - make_float2(v1.z, v1.w));
            }
            sums[5] += fabsf((dl - d1.x) * expf(-alr.x * third)) +
                       fabsf((dr - d1.y) * expf(-alr.y * third));
        }
        // SSIM, window centered at (x,y); valid centers 1..w-2 / 1..h-2.
        // x = estimate (le,re), y = target (lv,rv); L and R run in the two
        // lanes of each float2 (packed fp32).
        if (x >= 1 && x <= w - 2 && y >= 1 && y <= h - 2) {
            const float2 inv9 = f2(1.f / 9.f);
            const float2 c1 = f2(C1F), c2 = f2(C2F);
            const float2 two = f2(2.f), one = f2(1.f), half_ = f2(0.5f);
#pragma unroll 1
            for (int c = 0; c < 3; ++c) {
                float2 sX = f2(0.f), sY = f2(0.f);
                float2 sXX = f2(0.f), sYY = f2(0.f), sXY = f2(0.f);
#pragma unroll
                for (int dy = 0; dy < 3; ++dy) {
#pragma unroll
                    for (int dx = 0; dx < 3; ++dx) {
                        float4 v = simg[c][(ty + dy) * (TX + 2) + (tx + dx)];
                        float2 a = make_float2(v.x, v.y);
                        float2 bb = make_float2(v.z, v.w);
                        sX = sX + a;
                        sY = sY + bb;
                        sXX = sXX + a * a;
                        sYY = sYY + bb * bb;
                        sXY = sXY + a * bb;
                    }
                }
                float2 mx = sX * inv9, my = sY * inv9;
                float2 vx = sXX * inv9 - mx * mx;
                float2 vy = sYY * inv9 - my * my;
                float2 vxy = sXY * inv9 - mx * my;
                float2 num = (two * mx * my + c1) * (two * vxy + c2);
                float2 den = (mx * mx + my * my + c1) * (vx + vy + c2);
                float2 ss = make_float2(num.x / den.x, num.y / den.y);
                float2 v = (one - ss) * half_;
                sums[6] += fminf(fmaxf(v.x, 0.f), 1.f);
                sums[7] += fminf(fmaxf(v.y, 0.f), 1.f);
            }
        }
    }
    block_acc<8>(sums, acc);
}

__global__ void k_final(const float* __restrict__ acc, float* __restrict__ out,
                        int B, int H, int W) {
    if (threadIdx.x != 0 || blockIdx.x != 0) return;
    float img = 0.f, lr = 0.f, sm = 0.f;
    for (int i = 0; i < 4; ++i) {
        int r = 1 << i;
        int h = H / r, w = W / r;
        const float* a = acc + i * 8;
        float Nl1 = (float)B * 3.f * (float)h * (float)w;
        float Nss = (float)B * 3.f * (float)(h - 2) * (float)(w - 2);
        float Nlr = (float)B * (float)h * (float)w;
        float Nsx = (float)B * (float)h * (float)(w - 1);
        float Nsy = (float)B * (float)(h - 1) * (float)w;
        img += 0.5f * (a[6] / Nss) + 0.5f * (a[0] / Nl1)
             + 0.5f * (a[7] / Nss) + 0.5f * (a[1] / Nl1);
        lr += a[2] / Nlr + a[3] / Nlr;
        sm += (a[4] / Nsx + a[5] / Nsy) / (float)r;
    }
    out[0] = img + 0.1f * sm + 1.0f * lr;
}

extern "C" void kernel_launch(void* const* d_in, const int* in_sizes, int n_in,
                              void* d_out, int out_size, void* d_ws, size_t ws_size,
                              hipStream_t stream) {
    const int B = 16, H = 384, W = 768;
    const float* disp[4] = {(const float*)d_in[0], (const float*)d_in[1],
                            (const float*)d_in[2], (const float*)d_in[3]};
    const float* left = (const float*)d_in[4];
    const float* right = (const float*)d_in[5];
    float* out = (float*)d_out;

    float* acc = (float*)d_ws;
    float* pyr = acc + 256;
    long long sz1 = (long long)B * 3 * (H / 2) * (W / 2);
    long long sz2 = (long long)B * 3 * (H / 4) * (W / 4);
    long long sz3 = (long long)B * 3 * (H / 8) * (W / 8);
    float* lp1 = pyr;
    float* rp1 = lp1 + sz1;
    float* lp2 = rp1 + sz1;
    float* rp2 = lp2 + sz2;
    float* lp3 = rp2 + sz2;
    float* rp3 = lp3 + sz3;

    const int TB = 256;

    // one resize kernel for all pyramid levels (+ acc zeroing)
    {
        long long n1 = 2 * sz1, n2 = 2 * sz2, n3 = 2 * sz3;
        long long nt = n1 + n2 + n3;
        hipLaunchKernelGGL(k_resize_all, dim3((unsigned)((nt + TB - 1) / TB)), dim3(TB), 0, stream,
                           left, right, lp1, rp1, lp2, rp2, lp3, rp3, acc,
                           B, H, W, n1, n2, n3);
    }

    // one fused kernel for all 4 scales
    {
        const float* lp[4] = {left, lp1, lp2, lp3};
        const float* rp[4] = {right, rp1, rp2, rp3};
        ScaleArgs sa[4];
        int blk0 = 0;
        for (int i = 0; i < 4; ++i) {
            int r = 1 << i;
            int h = H / r, w = W / r;
            sa[i].disp = disp[i];
            sa[i].lp = lp[i];
            sa[i].rp = rp[i];
            sa[i].h = h;
            sa[i].w = w;
            sa[i].nx = w / TX;
            sa[i].ny = h / TY;
            sa[i].blk0 = blk0;
            blk0 += sa[i].nx * sa[i].ny * B;
        }
        hipLaunchKernelGGL(k_fused_all, dim3((unsigned)blk0), dim3(TB), 0, stream,
                           sa[0], sa[1], sa[2], sa[3], acc);
    }
    hipLaunchKernelGGL(k_final, dim3(1), dim3(64), 0, stream, acc, out, B, H, W);
}